// Round 8
// baseline (201.667 us; speedup 1.0000x reference)
//
#include <hip/hip_runtime.h>
#include <stdint.h>

#define NH   8
#define DIM  512
#define NP   1024
#define MNP  4096
#define BS   4
#define TOPK 32
#define DH   64

typedef unsigned short u16;
typedef __attribute__((ext_vector_type(8))) short bf16x8;
typedef __attribute__((ext_vector_type(4))) float f32x4;

__device__ __forceinline__ u16 f2bf(float f) {
    union { float f; unsigned u; } x; x.f = f;
    unsigned r = x.u + 0x7FFFu + ((x.u >> 16) & 1u);   // RNE
    return (u16)(r >> 16);
}
__device__ __forceinline__ float bf2f(u16 h) {
    union { unsigned u; float f; } x; x.u = ((unsigned)h) << 16;
    return x.f;
}
__device__ __forceinline__ unsigned pack2(float a, float b) {
    return (unsigned)f2bf(a) | ((unsigned)f2bf(b) << 16);
}

// async 16B global -> LDS (global_load_lds_dwordx4), wave-uniform base + lane*16
__device__ __forceinline__ void async16(const void* g, void* l) {
    __builtin_amdgcn_global_load_lds(
        (const __attribute__((address_space(1))) unsigned int*)g,
        (__attribute__((address_space(3))) unsigned int*)l, 16, 0, 0);
}

// ---------------- weights fp32 -> bf16 (3 MB; activations read fp32 by gemm)
__global__ void cvt_w(const float* __restrict__ W1, const float* __restrict__ W2,
                      const float* __restrict__ W3, u16* __restrict__ wall) {
    int i = (blockIdx.x * 256 + threadIdx.x) * 4;
    const float* s = (i < 262144) ? W1 + i : (i < 524288) ? W2 + (i - 262144)
                                           : W3 + (i - 524288);
    float4 val = *(const float4*)s;
    ushort4 o;
    o.x = f2bf(val.x); o.y = f2bf(val.y); o.z = f2bf(val.z); o.w = f2bf(val.w);
    *(ushort4*)(wall + i) = o;
}

// ---------------- fused projection GEMM, BM=32 BN=512(full) BK=32.
// Each fp32 A-row fetched from HBM exactly ONCE (no n-tile re-reads — the
// round-5 failure mode), converted in-register, staged to LDS. W streamed
// bf16 from L2 via async16. 1152 blocks (128 q + 512 k + 512 v m-tiles).
// LDS rows are 64 B (4 granules): swizzle slot=(g+(r>>1))&3 gives exact
// 2-way bank aliasing (free) on both ds_write and b128 fragment reads.
__global__ __launch_bounds__(256, 3)
void proj_gemm(const float* __restrict__ q, const float* __restrict__ k,
               const float* __restrict__ v, const u16* __restrict__ wall,
               const float* __restrict__ b1, const float* __restrict__ b2,
               const float* __restrict__ b3, u16* __restrict__ outall) {
    __shared__ u16 As[32 * 32];      // 2 KB
    __shared__ u16 Bs[512 * 32];     // 32 KB

    const int t = blockIdx.x;        // 0..1151
    int z, y;
    if (t < 128)      { z = 0; y = t; }          // q: 128 m-tiles
    else if (t < 640) { z = 1; y = t - 128; }    // k: 512 m-tiles
    else              { z = 2; y = t - 640; }    // v: 512 m-tiles

    const float* A32 = (z == 0) ? q : (z == 1) ? k : v;
    const u16* W = wall + (size_t)z * 262144;
    const float* bias = (z == 0) ? b1 : (z == 1) ? b2 : b3;
    const size_t coff = (z == 0) ? 0u : (z == 1) ? 2097152u : 10485760u;
    u16* C = outall + coff;

    const int tid  = threadIdx.x;
    const int bm   = y * 32;
    const int wave = tid >> 6;
    const int lane = tid & 63;
    const int l16  = lane & 15;
    const int quad = lane >> 4;

    // A staging map: thread -> (row, granule, half-granule)
    const int ar = tid >> 3;             // 0..31
    const int ag = (tid >> 1) & 3;       // logical granule 0..3
    const int ah = tid & 1;              // 16B half
    const int aslot = (ag + (ar >> 1)) & 3;
    const float* aptr = A32 + (size_t)(bm + ar) * 512 + ag * 8 + ah * 4;

    // B staging map: lane -> (row-in-16, LDS slot)
    const int brl = lane >> 2;           // 0..15
    const int bgs = lane & 3;            // LDS slot

    f32x4 acc[2][8] = {};

    float4 fA = *(const float4*)aptr;    // k0 = 0 prefetch

    for (int k0 = 0; k0 < 512; k0 += 32) {
        __syncthreads();                 // prev MFMA done reading LDS
        // A: pack current prefetch into swizzled LDS (uint2 per thread)
        {
            uint2 u = { pack2(fA.x, fA.y), pack2(fA.z, fA.w) };
            *(uint2*)(&As[ar * 32 + aslot * 8 + ah * 4]) = u;
        }
        // B: 512 rows x 32 cols, 8 async16 rounds per wave
#pragma unroll
        for (int a = 0; a < 8; a++) {
            int rowb = wave * 128 + a * 16;
            int row  = rowb + brl;
            int gf   = (bgs - (row >> 1)) & 3;   // fetch-permuted granule
            async16(W + (size_t)row * 512 + k0 + gf * 8,
                    &Bs[rowb * 32 + lane * 8]);
        }
        __syncthreads();                 // drains A ds_write + B async
        // prefetch next A chunk (lands during MFMA phase)
        if (k0 + 32 < 512) fA = *(const float4*)(aptr + k0 + 32);

        bf16x8 af[2], bfr[8];
#pragma unroll
        for (int i = 0; i < 2; i++) {
            int ra = i * 16 + l16;
            af[i] = *(const bf16x8*)(&As[ra * 32 + (((quad + (ra >> 1)) & 3) << 3)]);
        }
#pragma unroll
        for (int j = 0; j < 8; j++) {
            int rb = wave * 128 + j * 16 + l16;
            bfr[j] = *(const bf16x8*)(&Bs[rb * 32 + (((quad + (rb >> 1)) & 3) << 3)]);
        }
#pragma unroll
        for (int i = 0; i < 2; i++)
#pragma unroll
            for (int j = 0; j < 8; j++)
                acc[i][j] = __builtin_amdgcn_mfma_f32_16x16x32_bf16(
                    af[i], bfr[j], acc[i][j], 0, 0, 0);
    }
    // C/D layout: col=lane&15, row=quad*4+reg
#pragma unroll
    for (int i = 0; i < 2; i++) {
        int row = bm + i * 16 + quad * 4;
#pragma unroll
        for (int j = 0; j < 8; j++) {
            int col = wave * 128 + j * 16 + l16;
            float bv = bias[col];
#pragma unroll
            for (int r = 0; r < 4; r++)
                C[(size_t)(row + r) * 512 + col] = f2bf(acc[i][j][r] + bv);
        }
    }
}

// ---------------- barrier-free top-k gather attention: one WAVE per (n,b)
__global__ __launch_bounds__(256)
void attn_kernel(const u16* __restrict__ Qh, const u16* __restrict__ Kh,
                 const u16* __restrict__ Vh, const int* __restrict__ rns,
                 float* __restrict__ out) {
    __shared__ float sq[4][512];        // q row fp32, wave-private
    __shared__ float swt[4][32 * 9];    // weights [slot][head], stride-9 pad
    __shared__ int   srw[4][TOPK];      // gathered row offsets

    const int wv   = threadIdx.x >> 6;
    const int lane = threadIdx.x & 63;
    const int pair = blockIdx.x * 4 + wv;   // (n,b) id
    const int n = pair >> 2;
    const int b = pair & 3;
    const int s   = lane >> 1;   // slot
    const int sub = lane & 1;    // dim half

    int myidx = rns[(b * NP + n) * TOPK + s];
    int myrow = (myidx * BS + b) * DIM;
    if (sub == 0) srw[wv][s] = myrow;

    // dedupe: dup iff an earlier slot has the same index (matches ref set-mask)
    bool dup = false;
#pragma unroll
    for (int j = 0; j < TOPK; j++) {
        int other = __shfl(myidx, j * 2, 64);
        dup = dup || ((j < s) && (other == myidx));
    }

    // q row -> LDS fp32 (16B bf16 load per lane)
    {
        const u16* qrow = Qh + (size_t)pair * DIM;
        uint4 qv = *(const uint4*)(qrow + lane * 8);
        float4 f0 = { bf2f((u16)qv.x), bf2f((u16)(qv.x >> 16)),
                      bf2f((u16)qv.y), bf2f((u16)(qv.y >> 16)) };
        float4 f1 = { bf2f((u16)qv.z), bf2f((u16)(qv.z >> 16)),
                      bf2f((u16)qv.w), bf2f((u16)(qv.w >> 16)) };
        *(float4*)(&sq[wv][lane * 8])     = f0;
        *(float4*)(&sq[wv][lane * 8 + 4]) = f1;
    }
    __builtin_amdgcn_wave_barrier();   // wave-private LDS: scheduling pin only

    // scores: each lane computes 8 half-dots (its slot, its 32-dim half)
    const float* qw = sq[wv];
    float sc[NH];
#pragma unroll
    for (int h = 0; h < NH; h++) {
        const u16* kp = Kh + myrow + h * DH + sub * 32;
        const float* qp = qw + h * DH + sub * 32;
        float acc = 0.f;
#pragma unroll
        for (int d = 0; d < 32; d += 8) {
            uint4 kv = *(const uint4*)(kp + d);
            acc += qp[d + 0] * bf2f((u16)kv.x) + qp[d + 1] * bf2f((u16)(kv.x >> 16))
                 + qp[d + 2] * bf2f((u16)kv.y) + qp[d + 3] * bf2f((u16)(kv.y >> 16))
                 + qp[d + 4] * bf2f((u16)kv.z) + qp[d + 5] * bf2f((u16)(kv.z >> 16))
                 + qp[d + 6] * bf2f((u16)kv.w) + qp[d + 7] * bf2f((u16)(kv.w >> 16));
        }
        sc[h] = acc;
    }
#pragma unroll
    for (int h = 0; h < NH; h++) {
        sc[h] += __shfl_xor(sc[h], 1, 64);
        sc[h] = dup ? -1e30f : sc[h] * 0.125f;
    }
    // softmax over 32 slots via stride-{2..32} butterflies
    float w[NH];
#pragma unroll
    for (int h = 0; h < NH; h++) {
        float m = sc[h];
        m = fmaxf(m, __shfl_xor(m, 2, 64));
        m = fmaxf(m, __shfl_xor(m, 4, 64));
        m = fmaxf(m, __shfl_xor(m, 8, 64));
        m = fmaxf(m, __shfl_xor(m, 16, 64));
        m = fmaxf(m, __shfl_xor(m, 32, 64));
        float e = __expf(sc[h] - m);
        float t = e;
        t += __shfl_xor(t, 2, 64);
        t += __shfl_xor(t, 4, 64);
        t += __shfl_xor(t, 8, 64);
        t += __shfl_xor(t, 16, 64);
        t += __shfl_xor(t, 32, 64);
        w[h] = e / t;
    }
    if (sub == 0) {
#pragma unroll
        for (int h = 0; h < NH; h++) swt[wv][s * 9 + h] = w[h];
    }
    __builtin_amdgcn_wave_barrier();

    // V phase: lane covers 8 output elems (16B V load) x 32 slots
    const int h  = lane >> 3;
    const int e8 = lane * 8;
    float a[8] = {0, 0, 0, 0, 0, 0, 0, 0};
#pragma unroll 8
    for (int si = 0; si < TOPK; si++) {
        int   row = srw[wv][si];              // broadcast read
        float wgt = swt[wv][si * 9 + h];      // 8 consecutive addrs: no conflict
        uint4 vv = *(const uint4*)(Vh + row + e8);
        a[0] += wgt * bf2f((u16)vv.x); a[1] += wgt * bf2f((u16)(vv.x >> 16));
        a[2] += wgt * bf2f((u16)vv.y); a[3] += wgt * bf2f((u16)(vv.y >> 16));
        a[4] += wgt * bf2f((u16)vv.z); a[5] += wgt * bf2f((u16)(vv.z >> 16));
        a[6] += wgt * bf2f((u16)vv.w); a[7] += wgt * bf2f((u16)(vv.w >> 16));
    }
    float* op = out + (size_t)pair * DIM + e8;
    float4 o0 = {a[0], a[1], a[2], a[3]};
    float4 o1 = {a[4], a[5], a[6], a[7]};
    *(float4*)op       = o0;
    *((float4*)op + 1) = o1;
}

extern "C" void kernel_launch(void* const* d_in, const int* in_sizes, int n_in,
                              void* d_out, int out_size, void* d_ws, size_t ws_size,
                              hipStream_t stream) {
    const float* q  = (const float*)d_in[0];
    const float* k  = (const float*)d_in[1];
    const float* v  = (const float*)d_in[2];
    const int* rns  = (const int*)d_in[3];
    const float* W1 = (const float*)d_in[4];
    const float* b1 = (const float*)d_in[5];
    const float* W2 = (const float*)d_in[6];
    const float* b2 = (const float*)d_in[7];
    const float* W3 = (const float*)d_in[8];
    const float* b3 = (const float*)d_in[9];
    float* out = (float*)d_out;

    u16* ws   = (u16*)d_ws;
    u16* wall = ws;                        // 3 * 512*512 bf16 weights
    u16* proj = wall + 786432;             // Qh | Kh | Vh
    u16* Qh = proj;
    u16* Kh = proj + 2097152;
    u16* Vh = proj + 10485760;

    cvt_w<<<768, 256, 0, stream>>>(W1, W2, W3, wall);
    proj_gemm<<<1152, 256, 0, stream>>>(q, k, v, wall, b1, b2, b3, proj);
    attn_kernel<<<NP * BS / 4, 256, 0, stream>>>(Qh, Kh, Vh, rns, out);
}

// Round 9
// 185.176 us; speedup vs baseline: 1.0891x; 1.0891x over previous
//
#include <hip/hip_runtime.h>
#include <stdint.h>

#define NH   8
#define DIM  512
#define NP   1024
#define MNP  4096
#define BS   4
#define TOPK 32
#define DH   64

typedef unsigned short u16;
typedef __attribute__((ext_vector_type(8))) short bf16x8;
typedef __attribute__((ext_vector_type(4))) float f32x4;

__device__ __forceinline__ u16 f2bf(float f) {
    union { float f; unsigned u; } x; x.f = f;
    unsigned r = x.u + 0x7FFFu + ((x.u >> 16) & 1u);   // RNE
    return (u16)(r >> 16);
}
__device__ __forceinline__ float bf2f(u16 h) {
    union { unsigned u; float f; } x; x.u = ((unsigned)h) << 16;
    return x.f;
}

// async 16B global -> LDS (global_load_lds_dwordx4), wave-uniform base + lane*16
__device__ __forceinline__ void async16(const void* g, void* l) {
    __builtin_amdgcn_global_load_lds(
        (const __attribute__((address_space(1))) unsigned int*)g,
        (__attribute__((address_space(3))) unsigned int*)l, 16, 0, 0);
}

// ---------------- single fp32 -> bf16 pass: W1|W2|W3 -> wall, q|k|v -> act
// 4 coalesced passes per thread (4800 blocks): fewer addr computations/byte,
// 4 independent loads in flight.
__global__ void cvt_all(const float* __restrict__ W1, const float* __restrict__ W2,
                        const float* __restrict__ W3, const float* __restrict__ q,
                        const float* __restrict__ k,  const float* __restrict__ v,
                        u16* __restrict__ wall, u16* __restrict__ act) {
    const size_t base = ((size_t)blockIdx.x * 256 + threadIdx.x) * 4;
    const size_t gstride = (size_t)4800 * 256 * 4;   // elems per pass
#pragma unroll
    for (int g = 0; g < 4; g++) {
        size_t i = base + (size_t)g * gstride;
        const float* s; u16* d;
        if (i < 786432) {
            d = wall + i;
            s = (i < 262144) ? W1 + i : (i < 524288) ? W2 + (i - 262144) : W3 + (i - 524288);
        } else {
            size_t j = i - 786432;
            d = act + j;
            s = (j < 2097152) ? q + j : (j < 10485760) ? k + (j - 2097152) : v + (j - 10485760);
        }
        float4 val = *(const float4*)s;
        ushort4 o;
        o.x = f2bf(val.x); o.y = f2bf(val.y); o.z = f2bf(val.z); o.w = f2bf(val.w);
        *(ushort4*)d = o;
    }
}

// ---------------- fused projection GEMM (round-4 structure: 128x128x64,
// async16 both tiles, XOR-swizzled LDS granules).  Block mapping puts the 4
// n-tiles of one m-tile 288 apart: 288 % 8 == 0, so under round-robin
// bid->XCD they share an XCD L2 and A-tile re-reads become L2 hits.
__global__ __launch_bounds__(256, 4)
void proj_gemm(const u16* __restrict__ act, const u16* __restrict__ wall,
               const float* __restrict__ b1, const float* __restrict__ b2,
               const float* __restrict__ b3, u16* __restrict__ outall) {
    __shared__ u16 As[128 * 64];
    __shared__ u16 Bs[128 * 64];

    const int bid = blockIdx.x;        // 0..1151
    const int x = bid / 288;           // n-tile (same-m blocks 288 apart)
    const int t = bid % 288;           // m-tile id across q|k|v
    int z, y;
    if (t < 32)       { z = 0; y = t; }          // q: M=4096  (32 tiles)
    else if (t < 160) { z = 1; y = t - 32; }     // k: M=16384 (128 tiles)
    else              { z = 2; y = t - 160; }    // v: M=16384 (128 tiles)

    const size_t aoff = (z == 0) ? 0u : (z == 1) ? 2097152u : 10485760u;
    const u16* A = act + aoff;
    const u16* W = wall + (size_t)z * 262144;
    const float* bias = (z == 0) ? b1 : (z == 1) ? b2 : b3;
    u16* C = outall + aoff;

    const int tid  = threadIdx.x;
    const int bm   = y * 128;
    const int bn   = x * 128;
    const int wave = tid >> 6;
    const int lane = tid & 63;
    const int wm   = (wave & 1) * 64;
    const int wn   = (wave >> 1) * 64;
    const int l16  = lane & 15;
    const int quad = lane >> 4;

    const int srow = lane >> 3;                    // 0..7
    const int scol = ((lane & 7) ^ srow) * 8;      // swizzle-permuted granule

    f32x4 acc[4][4] = {};

    for (int k0 = 0; k0 < 512; k0 += 64) {
        __syncthreads();
#pragma unroll
        for (int r = 0; r < 4; r++) {
            int row = wave * 32 + r * 8;           // wave-uniform LDS base row
            async16(A + (size_t)(bm + row + srow) * 512 + k0 + scol,
                    &As[row * 64 + lane * 8]);
            async16(W + (size_t)(bn + row + srow) * 512 + k0 + scol,
                    &Bs[row * 64 + lane * 8]);
        }
        __syncthreads();   // drains vmcnt before barrier
#pragma unroll
        for (int kk = 0; kk < 64; kk += 32) {
            bf16x8 af[4], bfr[4];
            const int g = (kk >> 3) + quad;        // logical granule index
#pragma unroll
            for (int i = 0; i < 4; i++) {
                int ra = wm + i * 16 + l16;
                int rb = wn + i * 16 + l16;
                af[i]  = *(const bf16x8*)(&As[ra * 64 + ((g ^ (ra & 7)) << 3)]);
                bfr[i] = *(const bf16x8*)(&Bs[rb * 64 + ((g ^ (rb & 7)) << 3)]);
            }
#pragma unroll
            for (int i = 0; i < 4; i++)
#pragma unroll
                for (int j = 0; j < 4; j++)
                    acc[i][j] = __builtin_amdgcn_mfma_f32_16x16x32_bf16(
                        af[i], bfr[j], acc[i][j], 0, 0, 0);
        }
    }
    // C/D layout: col=lane&15, row=quad*4+reg
#pragma unroll
    for (int i = 0; i < 4; i++) {
        int row = bm + wm + i * 16 + quad * 4;
#pragma unroll
        for (int j = 0; j < 4; j++) {
            int col = bn + wn + j * 16 + l16;
            float bv = bias[col];
#pragma unroll
            for (int r = 0; r < 4; r++)
                C[(size_t)(row + r) * 512 + col] = f2bf(acc[i][j][r] + bv);
        }
    }
}

// ---------------- barrier-free top-k gather attention: one WAVE per (n,b)
__global__ __launch_bounds__(256)
void attn_kernel(const u16* __restrict__ Qh, const u16* __restrict__ Kh,
                 const u16* __restrict__ Vh, const int* __restrict__ rns,
                 float* __restrict__ out) {
    __shared__ float sq[4][512];        // q row fp32, wave-private
    __shared__ float swt[4][32 * 9];    // weights [slot][head], stride-9 pad
    __shared__ int   srw[4][TOPK];      // gathered row offsets

    const int wv   = threadIdx.x >> 6;
    const int lane = threadIdx.x & 63;
    const int pair = blockIdx.x * 4 + wv;   // (n,b) id
    const int n = pair >> 2;
    const int b = pair & 3;
    const int s   = lane >> 1;   // slot
    const int sub = lane & 1;    // dim half

    int myidx = rns[(b * NP + n) * TOPK + s];
    int myrow = (myidx * BS + b) * DIM;
    if (sub == 0) srw[wv][s] = myrow;

    // dedupe: dup iff an earlier slot has the same index (matches ref set-mask)
    bool dup = false;
#pragma unroll
    for (int j = 0; j < TOPK; j++) {
        int other = __shfl(myidx, j * 2, 64);
        dup = dup || ((j < s) && (other == myidx));
    }

    // q row -> LDS fp32 (16B bf16 load per lane)
    {
        const u16* qrow = Qh + (size_t)pair * DIM;
        uint4 qv = *(const uint4*)(qrow + lane * 8);
        float4 f0 = { bf2f((u16)qv.x), bf2f((u16)(qv.x >> 16)),
                      bf2f((u16)qv.y), bf2f((u16)(qv.y >> 16)) };
        float4 f1 = { bf2f((u16)qv.z), bf2f((u16)(qv.z >> 16)),
                      bf2f((u16)qv.w), bf2f((u16)(qv.w >> 16)) };
        *(float4*)(&sq[wv][lane * 8])     = f0;
        *(float4*)(&sq[wv][lane * 8 + 4]) = f1;
    }
    __builtin_amdgcn_wave_barrier();   // wave-private LDS: scheduling pin only

    // scores: each lane computes 8 half-dots (its slot, its 32-dim half)
    const float* qw = sq[wv];
    float sc[NH];
#pragma unroll
    for (int h = 0; h < NH; h++) {
        const u16* kp = Kh + myrow + h * DH + sub * 32;
        const float* qp = qw + h * DH + sub * 32;
        float acc = 0.f;
#pragma unroll
        for (int d = 0; d < 32; d += 8) {
            uint4 kv = *(const uint4*)(kp + d);
            acc += qp[d + 0] * bf2f((u16)kv.x) + qp[d + 1] * bf2f((u16)(kv.x >> 16))
                 + qp[d + 2] * bf2f((u16)kv.y) + qp[d + 3] * bf2f((u16)(kv.y >> 16))
                 + qp[d + 4] * bf2f((u16)kv.z) + qp[d + 5] * bf2f((u16)(kv.z >> 16))
                 + qp[d + 6] * bf2f((u16)kv.w) + qp[d + 7] * bf2f((u16)(kv.w >> 16));
        }
        sc[h] = acc;
    }
#pragma unroll
    for (int h = 0; h < NH; h++) {
        sc[h] += __shfl_xor(sc[h], 1, 64);
        sc[h] = dup ? -1e30f : sc[h] * 0.125f;
    }
    // softmax over 32 slots via stride-{2..32} butterflies
    float w[NH];
#pragma unroll
    for (int h = 0; h < NH; h++) {
        float m = sc[h];
        m = fmaxf(m, __shfl_xor(m, 2, 64));
        m = fmaxf(m, __shfl_xor(m, 4, 64));
        m = fmaxf(m, __shfl_xor(m, 8, 64));
        m = fmaxf(m, __shfl_xor(m, 16, 64));
        m = fmaxf(m, __shfl_xor(m, 32, 64));
        float e = __expf(sc[h] - m);
        float t = e;
        t += __shfl_xor(t, 2, 64);
        t += __shfl_xor(t, 4, 64);
        t += __shfl_xor(t, 8, 64);
        t += __shfl_xor(t, 16, 64);
        t += __shfl_xor(t, 32, 64);
        w[h] = e / t;
    }
    if (sub == 0) {
#pragma unroll
        for (int h = 0; h < NH; h++) swt[wv][s * 9 + h] = w[h];
    }
    __builtin_amdgcn_wave_barrier();

    // V phase: lane covers 8 output elems (16B V load) x 32 slots
    const int h  = lane >> 3;
    const int e8 = lane * 8;
    float a[8] = {0, 0, 0, 0, 0, 0, 0, 0};
#pragma unroll 8
    for (int si = 0; si < TOPK; si++) {
        int   row = srw[wv][si];              // broadcast read
        float wgt = swt[wv][si * 9 + h];      // 8 consecutive addrs: no conflict
        uint4 vv = *(const uint4*)(Vh + row + e8);
        a[0] += wgt * bf2f((u16)vv.x); a[1] += wgt * bf2f((u16)(vv.x >> 16));
        a[2] += wgt * bf2f((u16)vv.y); a[3] += wgt * bf2f((u16)(vv.y >> 16));
        a[4] += wgt * bf2f((u16)vv.z); a[5] += wgt * bf2f((u16)(vv.z >> 16));
        a[6] += wgt * bf2f((u16)vv.w); a[7] += wgt * bf2f((u16)(vv.w >> 16));
    }
    float* op = out + (size_t)pair * DIM + e8;
    float4 o0 = {a[0], a[1], a[2], a[3]};
    float4 o1 = {a[4], a[5], a[6], a[7]};
    *(float4*)op       = o0;
    *((float4*)op + 1) = o1;
}

extern "C" void kernel_launch(void* const* d_in, const int* in_sizes, int n_in,
                              void* d_out, int out_size, void* d_ws, size_t ws_size,
                              hipStream_t stream) {
    const float* q  = (const float*)d_in[0];
    const float* k  = (const float*)d_in[1];
    const float* v  = (const float*)d_in[2];
    const int* rns  = (const int*)d_in[3];
    const float* W1 = (const float*)d_in[4];
    const float* b1 = (const float*)d_in[5];
    const float* W2 = (const float*)d_in[6];
    const float* b2 = (const float*)d_in[7];
    const float* W3 = (const float*)d_in[8];
    const float* b3 = (const float*)d_in[9];
    float* out = (float*)d_out;

    u16* ws   = (u16*)d_ws;
    u16* wall = ws;                        // 3 * 512*512 bf16 weights
    u16* act  = wall + 786432;             // q(2097152) | k(8388608) | v(8388608)
    u16* proj = act + 18874368;            // Qh | Kh | Vh, same offsets
    u16* Qh = proj;
    u16* Kh = proj + 2097152;
    u16* Vh = proj + 10485760;

    cvt_all<<<4800, 256, 0, stream>>>(W1, W2, W3, q, k, v, wall, act);
    proj_gemm<<<1152, 256, 0, stream>>>(act, wall, b1, b2, b3, proj);
    attn_kernel<<<NP * BS / 4, 256, 0, stream>>>(Qh, Kh, Vh, rns, out);
}